// Round 9
// baseline (1003.137 us; speedup 1.0000x reference)
//
#include <hip/hip_runtime.h>
#include <hip/hip_bf16.h>

#define T_STEPS 512
#define BATCH   4096
#define ACT     16
#define HDIM    64

typedef short s8v __attribute__((ext_vector_type(8)));   // 8 bf16 MFMA A/B frag
typedef float f4v __attribute__((ext_vector_type(4)));   // MFMA C/D frag

#define MFMA16(A, B, C) __builtin_amdgcn_mfma_f32_16x16x32_bf16((A), (B), (C), 0, 0, 0)

__device__ __forceinline__ unsigned pkbf(float a, float b) {
    unsigned r;
    asm("v_cvt_pk_bf16_f32 %0, %1, %2" : "=v"(r) : "v"(a), "v"(b));
    return r;   // low16 = bf16(a), high16 = bf16(b)
}
__device__ __forceinline__ float hi16f(unsigned p) { return __builtin_bit_cast(float, p & 0xFFFF0000u); }
__device__ __forceinline__ unsigned short f2bf(float f) {
    unsigned u = __builtin_bit_cast(unsigned, f);
    u += 0x7FFFu + ((u >> 16) & 1u);
    return (unsigned short)(u >> 16);
}
__device__ __forceinline__ float bf2f(unsigned short b) {
    return __builtin_bit_cast(float, ((unsigned)b) << 16);
}
// tanh(x) = 1 - 2/(e^{2x}+1): exact at +-inf limits
__device__ __forceinline__ float ftanh(float x) {
    float e = __expf(2.0f * x);
    return fmaf(-2.0f, __builtin_amdgcn_rcpf(e + 1.0f), 1.0f);
}
struct i4x { int a, b, c, d; };
// 4 f32 -> interleaved (hi,lo) bf16 pairs: element 2j = bf16(v[j]), 2j+1 = bf16(residual)
__device__ __forceinline__ s8v pack4(f4v v) {
    unsigned p0 = pkbf(v[0], v[0]); float r0 = v[0] - hi16f(p0);
    unsigned p1 = pkbf(v[1], v[1]); float r1 = v[1] - hi16f(p1);
    unsigned p2 = pkbf(v[2], v[2]); float r2 = v[2] - hi16f(p2);
    unsigned p3 = pkbf(v[3], v[3]); float r3 = v[3] - hi16f(p3);
    i4x w{(int)pkbf(v[0], r0), (int)pkbf(v[1], r1), (int)pkbf(v[2], r2), (int)pkbf(v[3], r3)};
    return __builtin_bit_cast(s8v, w);
}

// Decoupled producer/consumer cell. Per block (one 16-row batch slice):
//   waves 0-3: recurrence (redundant-L1, own 16-ch L2 tile), setprio 1
//   waves 4-7: capture of z1 (free-running up to 4 steps ahead)
// No s_barrier in steady state: LDS seq flags only.
//   pf[T] = recur wave T's completed steps; zf[W] = capture wave W's produced steps.
__global__ __launch_bounds__(512, 2) void fused_cell(
    const float* __restrict__ x,  const float* __restrict__ h0,
    const float* __restrict__ g,  const float* __restrict__ a,
    const float* __restrict__ Wc1, const float* __restrict__ bc1,
    const float* __restrict__ Wc2, const float* __restrict__ bc2,
    const float* __restrict__ Wp1, const float* __restrict__ bp1,
    const float* __restrict__ Wp2, const float* __restrict__ bp2,
    float* __restrict__ outs, float* __restrict__ hfin, float* __restrict__ capt)
{
    __shared__ s8v   hx[2][4][64];      // double-buffered h frags (8 KB)
    __shared__ float zr[4][16][68];     // z1 ring, depth 4, stride 68 (2-way banks max)
    __shared__ int   flg[16];           // [0..3]=pf, [8..11]=zf

    const int tid = threadIdx.x;
    const int wv  = tid >> 6;
    const int T   = wv & 3;
    const bool capw = wv >= 4;
    const int l  = tid & 63;
    const int m  = l & 15;              // batch row within slice / A out-ch-local row
    const int q  = l >> 4;              // k-group; D out-ch group
    const int b0 = blockIdx.x << 4;

    volatile int* pf = (volatile int*)flg;
    volatile int* zf = (volatile int*)(flg + 8);
    if (tid < 16) flg[tid] = 0;

    if (!capw) {
        // ================= RECURRENCE WAVES =================
        s8v W1[4][5];          // [t1 out-tile][in frag]; f=4 = a-part rows 64..79
        s8v W2h[4], W2l[4];    // own L2 tile T
        f4v b1v[4], b2v;
        #pragma unroll
        for (int o = 0; o < 4; ++o) {
            #pragma unroll
            for (int f = 0; f < 4; ++f)
                #pragma unroll
                for (int e = 0; e < 8; ++e) {
                    const int j = f * 16 + q * 4 + (e >> 1);
                    W1[o][f][e] = (short)f2bf(Wp1[j * 64 + 16 * o + m]);
                }
            #pragma unroll
            for (int e = 0; e < 8; ++e) {
                const int j = 64 + q * 4 + (e >> 1);
                W1[o][4][e] = (short)f2bf(Wp1[j * 64 + 16 * o + m]);
            }
            b1v[o] = *(const f4v*)&bp1[16 * o + 4 * q];
        }
        #pragma unroll
        for (int f = 0; f < 4; ++f)
            #pragma unroll
            for (int e = 0; e < 8; ++e) {
                const int j = f * 16 + q * 4 + (e >> 1);
                float v2 = Wp2[j * 64 + 16 * T + m];
                unsigned short h2 = f2bf(v2);
                W2h[f][e] = (short)h2;
                W2l[f][e] = (short)f2bf(v2 - bf2f(h2));
            }
        b2v = *(const f4v*)&bp2[16 * T + 4 * q];

        // h0 -> hx[0]
        hx[0][T][l] = pack4(*(const f4v*)&h0[(long)(b0 + m) * 64 + 16 * T + 4 * q]);

        // a/g depth-2 register pipeline
        const long aoff = (long)(b0 + m) * ACT + 4 * q;
        const long goff = (long)(b0 + m);
        f4v aA = *(const f4v*)&a[aoff];
        f4v aB = *(const f4v*)&a[(long)BATCH * ACT + aoff];
        float gA = g[goff];
        float gB = g[(long)BATCH + goff];
        const float* apA = a + (long)2 * BATCH * ACT + aoff;
        const float* apB = a + (long)3 * BATCH * ACT + aoff;
        const float* gpA = g + (long)2 * BATCH + goff;
        const float* gpB = g + (long)3 * BATCH + goff;

        float* outp = &outs[(long)(b0 + m) * 64 + 16 * T + 4 * q];
        f4v hl = {0.f, 0.f, 0.f, 0.f};

        __syncthreads();   // flags + hx[0] visible; last barrier of the kernel
        __builtin_amdgcn_s_setprio(1);

#define L1T(o, dst) {                                                         \
    f4v p0 = b1v[o];                                                          \
    f4v p1 = {0.f, 0.f, 0.f, 0.f};                                            \
    p0 = MFMA16(W1[o][0], hf0, p0);                                           \
    p1 = MFMA16(W1[o][1], hf1, p1);                                           \
    p0 = MFMA16(W1[o][2], hf2, p0);                                           \
    p1 = MFMA16(W1[o][3], hf3, p1);                                           \
    p0 = MFMA16(W1[o][4], afr, p0);                                           \
    f4v tv_;                                                                  \
    _Pragma("unroll")                                                         \
    for (int r = 0; r < 4; ++r) tv_[r] = ftanh(p0[r] + p1[r]);                \
    dst = pack4(tv_);                                                         \
}

#define RSTEP(tt, AC, GC, APTR, GPTR) do {                                    \
    const int t_ = (tt);                                                      \
    const f4v aC_ = AC; const float gC_ = GC;                                 \
    while (pf[0] < t_ || pf[1] < t_ || pf[2] < t_ || pf[3] < t_ ||            \
           zf[0] <= t_ || zf[1] <= t_ || zf[2] <= t_ || zf[3] <= t_)          \
        __builtin_amdgcn_s_sleep(1);                                          \
    asm volatile("" ::: "memory");                                            \
    const f4v z1v = *(const f4v*)&zr[t_ & 3][m][16 * T + 4 * q];              \
    const s8v* hb = &hx[t_ & 1][0][0];                                        \
    const s8v hf0 = hb[l];                                                    \
    const s8v hf1 = hb[64 + l];                                               \
    const s8v hf2 = hb[128 + l];                                              \
    const s8v hf3 = hb[192 + l];                                              \
    const s8v afr = pack4(aC_);                                               \
    AC = *(const f4v*)APTR; if (t_ + 4 < T_STEPS) APTR += 2 * BATCH * ACT;    \
    GC = *GPTR;             if (t_ + 4 < T_STEPS) GPTR += 2 * BATCH;          \
    s8v tcf0, tcf1, tcf2, tcf3;                                               \
    L1T(0, tcf0) L1T(1, tcf1) L1T(2, tcf2) L1T(3, tcf3)                       \
    f4v c0 = b2v;                                                             \
    f4v c1 = {0.f, 0.f, 0.f, 0.f}, c2 = c1, c3 = c1;                          \
    c0 = MFMA16(W2h[0], tcf0, c0); c1 = MFMA16(W2h[1], tcf1, c1);             \
    c2 = MFMA16(W2h[2], tcf2, c2); c3 = MFMA16(W2h[3], tcf3, c3);             \
    c0 = MFMA16(W2l[0], tcf0, c0); c1 = MFMA16(W2l[1], tcf1, c1);             \
    c2 = MFMA16(W2l[2], tcf2, c2); c3 = MFMA16(W2l[3], tcf3, c3);             \
    f4v hv;                                                                   \
    _Pragma("unroll")                                                         \
    for (int r = 0; r < 4; ++r) {                                             \
        float z2 = ftanh((c0[r] + c1[r]) + (c2[r] + c3[r]));                  \
        hv[r] = fmaf(gC_, z2 - z1v[r], z1v[r]);                               \
    }                                                                         \
    *(f4v*)outp = hv; outp += (long)BATCH * HDIM;                             \
    hl = hv;                                                                  \
    hx[(t_ + 1) & 1][T][l] = pack4(hv);                                       \
    asm volatile("s_waitcnt lgkmcnt(0)" ::: "memory");                        \
    if (l == 0) pf[T] = t_ + 1;                                               \
} while (0)

        for (int t = 0; t < T_STEPS; t += 2) {
            RSTEP(t,     aA, gA, apA, gpA);
            RSTEP(t + 1, aB, gB, apB, gpB);
        }
#undef RSTEP
#undef L1T

        *(f4v*)&hfin[(long)(b0 + m) * 64 + 16 * T + 4 * q] = hl;

    } else {
        // ================= CAPTURE WAVES =================
        s8v C1[4][4];          // [t1 out-tile][x frag]
        s8v C2h[4], C2l[4];    // own z1 tile T
        f4v d1v[4], d2v;
        #pragma unroll
        for (int o = 0; o < 4; ++o) {
            #pragma unroll
            for (int f = 0; f < 4; ++f)
                #pragma unroll
                for (int e = 0; e < 8; ++e) {
                    const int j = f * 16 + q * 4 + (e >> 1);
                    C1[o][f][e] = (short)f2bf(Wc1[j * 64 + 16 * o + m]);
                }
            d1v[o] = *(const f4v*)&bc1[16 * o + 4 * q];
        }
        #pragma unroll
        for (int f = 0; f < 4; ++f)
            #pragma unroll
            for (int e = 0; e < 8; ++e) {
                const int j = f * 16 + q * 4 + (e >> 1);
                float v2 = Wc2[j * 64 + 16 * T + m];
                unsigned short h2 = f2bf(v2);
                C2h[f][e] = (short)h2;
                C2l[f][e] = (short)f2bf(v2 - bf2f(h2));
            }
        d2v = *(const f4v*)&bc2[16 * T + 4 * q];

        // x depth-2 register pipeline (per-lane base, 4 tile frags each)
        const float* bx = x + (long)(b0 + m) * 64 + 4 * q;
        f4v XA0 = *(const f4v*)(bx);
        f4v XA1 = *(const f4v*)(bx + 16);
        f4v XA2 = *(const f4v*)(bx + 32);
        f4v XA3 = *(const f4v*)(bx + 48);
        const float* bx1 = bx + (long)BATCH * HDIM;
        f4v XB0 = *(const f4v*)(bx1);
        f4v XB1 = *(const f4v*)(bx1 + 16);
        f4v XB2 = *(const f4v*)(bx1 + 32);
        f4v XB3 = *(const f4v*)(bx1 + 48);
        const float* xpA = bx + (long)2 * BATCH * HDIM;
        const float* xpB = bx + (long)3 * BATCH * HDIM;

        float* cp = &capt[(long)(b0 + m) * 64 + 16 * T + 4 * q];

        __syncthreads();

#define CL1T(o, dst) {                                                        \
    f4v p0 = d1v[o];                                                          \
    f4v p1 = {0.f, 0.f, 0.f, 0.f};                                            \
    p0 = MFMA16(C1[o][0], xf0, p0);                                           \
    p1 = MFMA16(C1[o][1], xf1, p1);                                           \
    p0 = MFMA16(C1[o][2], xf2, p0);                                           \
    p1 = MFMA16(C1[o][3], xf3, p1);                                           \
    f4v tv_;                                                                  \
    _Pragma("unroll")                                                         \
    for (int r = 0; r < 4; ++r) tv_[r] = ftanh(p0[r] + p1[r]);                \
    dst = pack4(tv_);                                                         \
}

#define CSTEP(tt, X0, X1, X2, X3, XPTR) do {                                  \
    const int t_ = (tt);                                                      \
    if (t_ >= 4) {                                                            \
        const int want = t_ - 3;                                              \
        while (pf[0] < want || pf[1] < want || pf[2] < want || pf[3] < want)  \
            __builtin_amdgcn_s_sleep(1);                                      \
        asm volatile("" ::: "memory");                                        \
    }                                                                         \
    const s8v xf0 = pack4(X0);                                                \
    const s8v xf1 = pack4(X1);                                                \
    const s8v xf2 = pack4(X2);                                                \
    const s8v xf3 = pack4(X3);                                                \
    X0 = *(const f4v*)(XPTR);                                                 \
    X1 = *(const f4v*)(XPTR + 16);                                            \
    X2 = *(const f4v*)(XPTR + 32);                                            \
    X3 = *(const f4v*)(XPTR + 48);                                            \
    if (t_ + 4 < T_STEPS) XPTR += (long)2 * BATCH * HDIM;                     \
    s8v tcf0, tcf1, tcf2, tcf3;                                               \
    CL1T(0, tcf0) CL1T(1, tcf1) CL1T(2, tcf2) CL1T(3, tcf3)                   \
    f4v c0 = d2v;                                                             \
    f4v c1 = {0.f, 0.f, 0.f, 0.f}, c2 = c1, c3 = c1;                          \
    c0 = MFMA16(C2h[0], tcf0, c0); c1 = MFMA16(C2h[1], tcf1, c1);             \
    c2 = MFMA16(C2h[2], tcf2, c2); c3 = MFMA16(C2h[3], tcf3, c3);             \
    c0 = MFMA16(C2l[0], tcf0, c0); c1 = MFMA16(C2l[1], tcf1, c1);             \
    c2 = MFMA16(C2l[2], tcf2, c2); c3 = MFMA16(C2l[3], tcf3, c3);             \
    f4v zv;                                                                   \
    _Pragma("unroll")                                                         \
    for (int r = 0; r < 4; ++r) zv[r] = ftanh((c0[r] + c1[r]) + (c2[r] + c3[r])); \
    *(f4v*)&zr[t_ & 3][m][16 * T + 4 * q] = zv;                               \
    *(f4v*)cp = zv; cp += (long)BATCH * HDIM;                                 \
    asm volatile("s_waitcnt lgkmcnt(0)" ::: "memory");                        \
    if (l == 0) zf[T] = t_ + 1;                                               \
} while (0)

        for (int t = 0; t < T_STEPS; t += 2) {
            CSTEP(t,     XA0, XA1, XA2, XA3, xpA);
            CSTEP(t + 1, XB0, XB1, XB2, XB3, xpB);
        }
#undef CSTEP
#undef CL1T
    }
}

extern "C" void kernel_launch(void* const* d_in, const int* in_sizes, int n_in,
                              void* d_out, int out_size, void* d_ws, size_t ws_size,
                              hipStream_t stream) {
    const float* x   = (const float*)d_in[0];
    const float* h0  = (const float*)d_in[1];
    const float* g   = (const float*)d_in[2];
    const float* a   = (const float*)d_in[3];
    const float* Wc1 = (const float*)d_in[4];
    const float* bc1 = (const float*)d_in[5];
    const float* Wc2 = (const float*)d_in[6];
    const float* bc2 = (const float*)d_in[7];
    const float* Wp1 = (const float*)d_in[8];
    const float* bp1 = (const float*)d_in[9];
    const float* Wp2 = (const float*)d_in[10];
    const float* bp2 = (const float*)d_in[11];

    float* outs = (float*)d_out;
    float* hfin = outs + (long)T_STEPS * BATCH * HDIM;
    float* capt = hfin + (long)BATCH * HDIM;

    fused_cell<<<BATCH / 16, 512, 0, stream>>>(
        x, h0, g, a, Wc1, bc1, Wc2, bc2, Wp1, bp1, Wp2, bp2, outs, hfin, capt);
}